// Round 6
// baseline (144.590 us; speedup 1.0000x reference)
//
#include <hip/hip_runtime.h>
#include <math.h>

#define BB 8
#define CC 128
#define NN 4096   // W*H

typedef _Float16 f16;
typedef _Float16 f16x2 __attribute__((ext_vector_type(2)));
typedef _Float16 f16x4v __attribute__((ext_vector_type(4)));
typedef _Float16 f16x8 __attribute__((ext_vector_type(8)));
typedef float f32x4v __attribute__((ext_vector_type(4)));
typedef float f32x16 __attribute__((ext_vector_type(16)));
typedef int i32x4 __attribute__((ext_vector_type(4)));

#if __has_builtin(__builtin_amdgcn_exp2f)
#define EXP2(x) __builtin_amdgcn_exp2f(x)
#else
#define EXP2(x) __expf((x)*0.69314718056f)
#endif

#if __has_builtin(__builtin_amdgcn_cvt_pkrtz) && __has_builtin(__builtin_amdgcn_fdot2)
#define CVTPK(a,b)    __builtin_amdgcn_cvt_pkrtz((a),(b))
#define FDOT2(pk,acc) __builtin_amdgcn_fdot2((pk), one2_, (acc), false)
#else
static __device__ inline f16x2 cvtpk_fb(float a, float b){ f16x2 r; r[0]=(f16)a; r[1]=(f16)b; return r; }
#define CVTPK(a,b)    cvtpk_fb((a),(b))
#define FDOT2(pk,acc) ((acc) + (float)(pk)[0] + (float)(pk)[1])
#endif

// Q rows pre-scaled by 0.25*log2(e): softmax exp is one native v_exp_f32;
// the -SHIFT bias rides in the MFMA C operand.
#define QSCALE 0.360673760222f   // 0.25 * log2(e)
#define SHIFT  5.770780163555f   // 4.0 * log2(e)

// Wf scratch lives in the tail of d_out (attn rewrites d_out afterwards).
#define WF_BYTES 65536

// ---------------------------------------------------------------------------
// prep: stack Wq*QSCALE (rows 0-15), Wk (16-31), Wv (32-159) as f16 in
// 32x32x16 A-fragment order. biasS f32[160] likewise stacked.
// ---------------------------------------------------------------------------
__global__ __launch_bounds__(256)
void prep_kernel(const float* __restrict__ Wq, const float* __restrict__ bq,
                 const float* __restrict__ Wk, const float* __restrict__ bk,
                 const float* __restrict__ Wv, const float* __restrict__ bv,
                 f16* __restrict__ Wf, float* __restrict__ biasS)
{
    const int tg = blockIdx.x*256 + threadIdx.x;   // 0..2559
    if (tg < 2560) {
        const int mt = tg >> 9, ks = (tg >> 6) & 7, l = tg & 63;
        const int n32 = l & 31, h = l >> 5;
        const int r = mt*32 + n32;
        f16x8 v8;
        #pragma unroll
        for (int i = 0; i < 8; i++) {
            int c = ks*16 + 8*h + i;
            float wv_;
            if (r < 16)      wv_ = QSCALE * Wq[r*CC + c];
            else if (r < 32) wv_ = Wk[(r-16)*CC + c];
            else             wv_ = Wv[(r-32)*CC + c];
            v8[i] = (f16)wv_;
        }
        *(f16x8*)&Wf[(size_t)tg*8] = v8;
    }
    if (blockIdx.x == 0 && threadIdx.x < 160) {
        int r = threadIdx.x;
        biasS[r] = r < 16 ? QSCALE*bq[r] : (r < 32 ? bk[r-16] : bv[r-32]);
    }
}

// ---------------------------------------------------------------------------
// Projection as MFMA mini-GEMM: OUT[160][128px] = Wst(160x128) * x(128x128px).
// grid 256 (b = bx&7, pt = bx>>3), block 256 = 4 waves, wave = 32-pixel
// n-tile, K=128 (8 ksteps), 40 MFMAs/wave. Non-temporal x loads keep L2 for
// Qt/Kt/Vf. Epilogue: Qt/Kt pixel-major; V via LDS -> sigma-ordered Vf:
//   Vf[b][kt64][frag=kc*4+ct][l][i] =
//     V[c=ct*32+(l&31)][key=kt64*64 + kc*16 + (i&3)+8*(i>>2)+4*(l>>5)]
// ---------------------------------------------------------------------------
__global__ __launch_bounds__(256)
void proj_kernel(const float* __restrict__ x, const f16* __restrict__ Wf,
                 const float* __restrict__ biasS,
                 f16* __restrict__ Qt, f16* __restrict__ Kt, f16* __restrict__ Vf)
{
    __shared__ __align__(16) f16 Vl[CC*140];   // 35 KB, stride 140 halfs

    const int tid  = threadIdx.x;
    const int lane = tid & 63;
    const int wv   = tid >> 6;
    const int b    = blockIdx.x & 7;
    const int pt   = blockIdx.x >> 3;      // 0..31
    const int n32  = lane & 31;
    const int half = lane >> 5;
    const int p    = pt*128 + wv*32 + n32;

    const float* xp = x + (size_t)b*CC*NN + p;
    f16x8 xf[8];
    #pragma unroll
    for (int ks = 0; ks < 8; ks++) {
        float xv[8];
        #pragma unroll
        for (int i = 0; i < 8; i++)
            xv[i] = __builtin_nontemporal_load(&xp[(size_t)(ks*16 + 8*half + i)*NN]);
        #pragma unroll
        for (int i = 0; i < 8; i++) xf[ks][i] = (f16)xv[i];
    }

    f32x16 acc[5];
    #pragma unroll
    for (int mt = 0; mt < 5; mt++) acc[mt] = (f32x16)0.0f;
    #pragma unroll
    for (int ks = 0; ks < 8; ks++) {
        #pragma unroll
        for (int mt = 0; mt < 5; mt++) {
            f16x8 wfr = *(const f16x8*)&Wf[((size_t)(mt*8 + ks)*64 + lane)*8];
            acc[mt] = __builtin_amdgcn_mfma_f32_32x32x16_f16(wfr, xf[ks], acc[mt], 0, 0, 0);
        }
    }

    #pragma unroll
    for (int mt = 0; mt < 5; mt++) {
        #pragma unroll
        for (int q = 0; q < 4; q++) {
            float4 b4 = *(const float4*)&biasS[mt*32 + q*8 + 4*half];
            acc[mt][q*4+0] += b4.x; acc[mt][q*4+1] += b4.y;
            acc[mt][q*4+2] += b4.z; acc[mt][q*4+3] += b4.w;
        }
    }

    // mt0: rows 0-15 = Q, 16-31 = K
    {
        size_t qkoff = ((size_t)b*NN + p)*16;
        f16x4v s0, s1, s2, s3;
        #pragma unroll
        for (int i = 0; i < 4; i++) {
            s0[i] = (f16)acc[0][i];    s1[i] = (f16)acc[0][4+i];
            s2[i] = (f16)acc[0][8+i];  s3[i] = (f16)acc[0][12+i];
        }
        *(f16x4v*)&Qt[qkoff + 4*half]     = s0;
        *(f16x4v*)&Qt[qkoff + 8 + 4*half] = s1;
        *(f16x4v*)&Kt[qkoff + 4*half]     = s2;
        *(f16x4v*)&Kt[qkoff + 8 + 4*half] = s3;
    }

    // mt1-4: V channels -> LDS [c][local pixel]
    #pragma unroll
    for (int mt = 1; mt < 5; mt++) {
        #pragma unroll
        for (int g = 0; g < 16; g++) {
            int c = (mt-1)*32 + (g & 3) + 8*(g >> 2) + 4*half;
            Vl[c*140 + wv*32 + n32] = (f16)acc[mt][g];
        }
    }
    __syncthreads();

    // sigma-ordered Vf writeout
    #pragma unroll
    for (int pass = 0; pass < 8; pass++) {
        int item = pass*256 + tid;
        int l    = item & 63;
        int f    = (item >> 6) & 15;       // kc*4 + ct
        int ktl  = item >> 10;             // 0..1 (64-px tile within block)
        int c16  = f >> 2, ct = f & 3;
        int li   = l & 31, h2 = l >> 5;
        const f16* src = &Vl[(ct*32 + li)*140 + ktl*64 + c16*16 + 4*h2];
        f16x4v lo = *(const f16x4v*)&src[0];
        f16x4v hi = *(const f16x4v*)&src[8];
        f16x8 v8;
        #pragma unroll
        for (int i = 0; i < 4; i++) { v8[i] = lo[i]; v8[4+i] = hi[i]; }
        int ktg = pt*2 + ktl;              // 64-key tile index
        *(f16x8*)&Vf[((((size_t)b*64 + ktg)*16 + c16*4 + ct)*64 + l)*8] = v8;
    }
}

// ---------------------------------------------------------------------------
// Attention r14: occupancy-first restructure. r8/r9/r10/r13 all land 54-59us
// with MFMA 29% + VALU 31% + ~40% dual-idle at 2 waves/SIMD -- latency can't
// be hidden by 2 in-phase waves, and r11/r12 proved the old wave shape can't
// fit 4 waves/SIMD (spill). New shape fits ~110 unified regs:
//   grid 1024 (b = bx&7, qt = bx>>3 -> 32 queries/block), block 256 = 4
//   waves; wave w owns channel tile ct=w: of[1] (16 acc) + vpf[4] (16).
//   No key split: each wave sweeps all 64 key tiles; NO combine epilogue.
//   QK+exp rotates: wave w produces St-half (w&1) on tiles of parity (w>>1)
//   (1 QK MFMA + 16 exps per turn, zero redundancy), P exchanged via 8KB
//   LDS (2 parity regions), lgkm-only barriers (1/tile).
//   exp path: cvt_pkrtz packs P pairs, fdot2 folds the denominator.
// Key property: a block's 4 waves sit on 4 DIFFERENT SIMDs, so each SIMD
// hosts 4 waves from 4 different blocks -> barriers never lockstep a SIMD;
// independent blocks' MFMA/VALU/TRANS phases interleave.
// V traffic doubles (per-32q re-read) -- L2 at 1/3 ceiling has the headroom.
// __launch_bounds__(256,4) caps VGPR 128; spill canary = FETCH/WRITE bloat.
// ---------------------------------------------------------------------------
__global__ __launch_bounds__(256, 4)
void attn_kernel(const f16* __restrict__ Qt, const f16* __restrict__ Kt,
                 const f16* __restrict__ Vf, float* __restrict__ out)
{
    __shared__ __align__(16) unsigned char lds_raw[19072];
    // main loop: Pex f16 [2 par][4 frag][64 lane][8] = 8 KB at 0
    // epilogue:  Tb f32[128][36] = 18432 at 0 (aliases Pex, barriered);
    //            ls_part f32[128] at 18432; ls_inv f32[32] at 18944

    const int tid  = threadIdx.x;
    const int lane = tid & 63;
    const int w    = tid >> 6;         // 0..3 = channel tile ct
    const int b    = blockIdx.x & 7;
    const int qt   = blockIdx.x >> 3;  // 0..127
    const int q0   = qt*32;
    const int n32  = lane & 31;
    const int half = lane >> 5;
    const int myhalf = w & 1;          // St-half this wave produces
    const int mypar  = w >> 1;         // tile parity this wave produces

    const f16* vb = Vf + (size_t)b*64*16*512;
    const f16* kb = Kt + (size_t)b*NN*16;
    const f16x8 qf = *(const f16x8*)&Qt[((size_t)b*NN + q0 + n32)*16 + half*8];

    f16* Pex = (f16*)lds_raw;
    const auto one2_ = CVTPK(1.0f, 1.0f);

    f32x16 of = (f32x16)0.0f;
    float ls = 0.0f;

    // prime: K fragment for this wave's first producing tile; V frags tile 0
    f16x8 kf = *(const f16x8*)&kb[((size_t)(mypar*64 + myhalf*32 + n32))*16 + half*8];
    f16x8 vpf[4];
    #pragma unroll
    for (int kc = 0; kc < 4; kc++)
        vpf[kc] = *(const f16x8*)&vb[((size_t)(kc*4 + w)*64 + lane)*8];

    // produce: exp St -> packed P frags (2*myhalf, 2*myhalf+1) in region PAR;
    // fdot2 folds the softmax denominator while packing.
#define PROD(ST, PAR)                                                          \
    {                                                                          \
        i32x4 lo_, hi_;                                                        \
        _Pragma("unroll")                                                      \
        for (int e = 0; e < 8; e++) {                                          \
            float ea_ = EXP2((ST)[2*e]);                                       \
            float eb_ = EXP2((ST)[2*e+1]);                                     \
            auto pk_ = CVTPK(ea_, eb_);                                        \
            ls = FDOT2(pk_, ls);                                               \
            if (e < 4) lo_[e]   = __builtin_bit_cast(int, pk_);                \
            else       hi_[e-4] = __builtin_bit_cast(int, pk_);                \
        }                                                                      \
        f16* wr_ = &Pex[((size_t)((PAR)*4 + 2*myhalf)*64 + lane)*8];           \
        *(i32x4*)&wr_[0]   = lo_;                                              \
        *(i32x4*)&wr_[512] = hi_;                                              \
    }

    for (int kt2 = 0; kt2 < 64; kt2 += 2) {
        // ---- tile kt2 (even): producers = waves 0,1 ----
        if (w < 2) {
            f32x16 St = __builtin_amdgcn_mfma_f32_32x32x16_f16(kf, qf, (f32x16)(-SHIFT), 0, 0, 0);
            {
                const int tn = (kt2 + 2 < 64) ? kt2 + 2 : kt2;
                kf = *(const f16x8*)&kb[((size_t)(tn*64 + myhalf*32 + n32))*16 + half*8];
            }
            PROD(St, 0)
        }
        // LDS-only drain: global K/V prefetches stay in flight
        asm volatile("s_waitcnt lgkmcnt(0)\n\ts_barrier" ::: "memory");
        {
            const f16* vtn = vb + (size_t)(kt2 + 1)*8192;
            #pragma unroll
            for (int kc = 0; kc < 4; kc++) {
                f16x8 pq = *(const f16x8*)&Pex[((size_t)kc*64 + lane)*8];
                f16x8 vc = vpf[kc];
                vpf[kc] = *(const f16x8*)&vtn[((size_t)(kc*4 + w)*64 + lane)*8];
                of = __builtin_amdgcn_mfma_f32_32x32x16_f16(pq, vc, of, 0, 0, 0);
            }
        }
        // ---- tile kt2+1 (odd): producers = waves 2,3 ----
        if (w >= 2) {
            f32x16 St = __builtin_amdgcn_mfma_f32_32x32x16_f16(kf, qf, (f32x16)(-SHIFT), 0, 0, 0);
            {
                const int tn = (kt2 + 3 < 64) ? kt2 + 3 : kt2 + 1;
                kf = *(const f16x8*)&kb[((size_t)(tn*64 + myhalf*32 + n32))*16 + half*8];
            }
            PROD(St, 1)
        }
        asm volatile("s_waitcnt lgkmcnt(0)\n\ts_barrier" ::: "memory");
        {
            const int tv = (kt2 + 2 < 64) ? kt2 + 2 : 63;
            const f16* vtn = vb + (size_t)tv*8192;
            #pragma unroll
            for (int kc = 0; kc < 4; kc++) {
                f16x8 pq = *(const f16x8*)&Pex[((size_t)(4 + kc)*64 + lane)*8];
                f16x8 vc = vpf[kc];
                vpf[kc] = *(const f16x8*)&vtn[((size_t)(kc*4 + w)*64 + lane)*8];
                of = __builtin_amdgcn_mfma_f32_32x32x16_f16(pq, vc, of, 0, 0, 0);
            }
        }
    }
#undef PROD

    // ---- epilogue: 4-way ls reduction, normalize, transpose, store ----
    float ls2 = ls + __shfl_xor(ls, 32);     // merge row-groups -> per-query n32
    __syncthreads();
    float* ls_part = (float*)(lds_raw + 18432);
    float* ls_inv  = (float*)(lds_raw + 18944);
    if (lane < 32) ls_part[w*32 + n32] = ls2;
    __syncthreads();
    if (w == 0 && lane < 32)
        ls_inv[n32] = 1.0f / (ls_part[n32] + ls_part[32 + n32] +
                              ls_part[64 + n32] + ls_part[96 + n32]);
    __syncthreads();
    float* Tb = (float*)lds_raw;             // [128 c][36], aliases Pex
    {
        f32x4v iv[4];
        #pragma unroll
        for (int t = 0; t < 4; t++)
            iv[t] = *(const f32x4v*)&ls_inv[t*8 + 4*half];
        #pragma unroll
        for (int g = 0; g < 16; g++) {
            int row = (g & 3) + 8*(g >> 2) + 4*half;     // query-within-32
            Tb[(size_t)(w*32 + n32)*36 + row] = of[g] * iv[g >> 2][g & 3];
        }
    }
    __syncthreads();
    #pragma unroll
    for (int it = 0; it < 4; it++) {
        int idx = it*256 + tid;
        int c = idx >> 3, qg = idx & 7;
        f32x4v v = *(const f32x4v*)&Tb[(size_t)c*36 + qg*4];
        // non-temporal: keep the 16 MB output stream out of L2
        __builtin_nontemporal_store(v,
            (f32x4v*)&out[((size_t)b*CC + c)*NN + q0 + qg*4]);
    }
}

extern "C" void kernel_launch(void* const* d_in, const int* in_sizes, int n_in,
                              void* d_out, int out_size, void* d_ws, size_t ws_size,
                              hipStream_t stream) {
    const float* x  = (const float*)d_in[0];
    const float* Wq = (const float*)d_in[1];
    const float* bq = (const float*)d_in[2];
    const float* Wk = (const float*)d_in[3];
    const float* bk = (const float*)d_in[4];
    const float* Wv = (const float*)d_in[5];
    const float* bv = (const float*)d_in[6];
    float* out = (float*)d_out;

    // workspace: Qt,Kt f16 [B][N][16] (1MB each), Vf f16 sigma-fragments (8MB)
    f16* Qw = (f16*)d_ws;
    f16* Kw = Qw + (size_t)BB*NN*16;
    f16* Vw = Kw + (size_t)BB*NN*16;
    unsigned char* tail = (unsigned char*)d_out + (size_t)out_size*4 - WF_BYTES;
    f16*   Wf    = (f16*)tail;
    float* biasS = (float*)(tail + 49152);

    hipLaunchKernelGGL(prep_kernel, dim3(10), dim3(256), 0, stream,
                       Wq, bq, Wk, bk, Wv, bv, Wf, biasS);
    hipLaunchKernelGGL(proj_kernel, dim3(256), dim3(256), 0, stream,
                       x, Wf, biasS, Qw, Kw, Vw);
    hipLaunchKernelGGL(attn_kernel, dim3(1024), dim3(256), 0, stream,
                       Qw, Kw, Vw, out);
}